// Round 8
// baseline (371.226 us; speedup 1.0000x reference)
//
#include <hip/hip_runtime.h>
#include <cstdint>
#include <cstddef>

typedef _Float16 h16;
typedef _Float16 h16x4 __attribute__((ext_vector_type(4)));
typedef _Float16 h16x8 __attribute__((ext_vector_type(8)));
typedef __fp16 fp16x2 __attribute__((ext_vector_type(2)));
typedef float f32x4 __attribute__((ext_vector_type(4)));

#define LOG2E 1.44269504088896f
#define QSCALE (0.125f * LOG2E)
#define THR 11.0f

static __device__ __forceinline__ f32x4 mfma_f16(h16x8 a, h16x8 b, f32x4 c) {
  return __builtin_amdgcn_mfma_f32_16x16x32_f16(a, b, c, 0, 0, 0);
}

static __device__ __forceinline__ void gload_lds16(const void* g, void* s) {
  __builtin_amdgcn_global_load_lds(
      (__attribute__((address_space(1))) void*)(uintptr_t)g,
      (__attribute__((address_space(3))) void*)s, 16, 0, 0);
}

// ---------------- fp32 -> fp16 convert (vectorized) ----------------
__global__ __launch_bounds__(256) void k_cvt(const float* __restrict__ in,
                                             h16* __restrict__ out, int n) {
  int i = (blockIdx.x * 256 + threadIdx.x) * 8;
  if (i >= n) return;
  float4 a = *(const float4*)(in + i);
  float4 b = *(const float4*)(in + i + 4);
  h16x8 o;
  o[0] = (h16)a.x; o[1] = (h16)a.y; o[2] = (h16)a.z; o[3] = (h16)a.w;
  o[4] = (h16)b.x; o[5] = (h16)b.y; o[6] = (h16)b.z; o[7] = (h16)b.w;
  *(h16x8*)(out + i) = o;
}

// ---------------- fp32 [R][C] -> fp16 [C][R] transpose-convert ----------------
__global__ __launch_bounds__(256) void k_tr_cvt(const float* __restrict__ in,
                                                h16* __restrict__ out, int R, int C) {
  __shared__ float tile[32][33];
  int c0 = blockIdx.x * 32, r0 = blockIdx.y * 32;
  int tx = threadIdx.x & 31, ty = threadIdx.x >> 5;
#pragma unroll
  for (int i = 0; i < 4; i++) {
    int r = ty + i * 8;
    tile[r][tx] = in[(size_t)(r0 + r) * C + c0 + tx];
  }
  __syncthreads();
#pragma unroll
  for (int i = 0; i < 4; i++) {
    int c = ty + i * 8;
    out[(size_t)(c0 + c) * R + r0 + tx] = (h16)tile[tx][c];
  }
}

// ---------------- 128x128 tile GEMM mainloop (m97-structure), BK=32 ----------------
// LDS tiles [128][32] h16 with chunk-XOR swizzle: the 8-elem chunk at
// (row, ch) holds global (row, ch ^ ((row>>1)&3)). Fragment reads are then
// bank-conflict-free (R5 measured 6.29M conflicts from the linear layout).
// Staged via pre-swizzled global source (linear LDS dest, rule 21).
static __device__ __forceinline__ void gemm_main(const h16* __restrict__ A,
                                                 const h16* __restrict__ BT,
                                                 int K, int m0, int n0,
                                                 h16* sA, h16* sB, f32x4 acc[4][4]) {
  const int t = threadIdx.x;
  const int l = t & 63, w = t >> 6;
  const int lm = l & 15, lh = l >> 4;
  const int wm = (w >> 1) * 64, wn = (w & 1) * 64;

  const int srow = t >> 2;                       // 0..63
  const int schunk = (t & 3) ^ ((srow >> 1) & 3);  // pre-swizzled source chunk
  const h16* gA0 = A + (size_t)(m0 + srow) * K + schunk * 8;
  const h16* gB0 = BT + (size_t)(n0 + srow) * K + schunk * 8;
  h16* sAw = sA + w * 512;  // wave-uniform LDS staging base (elements)
  h16* sBw = sB + w * 512;

  const int swa = ((lm >> 1) & 3);  // read-side XOR (row bits within fragment)

  for (int k0 = 0; k0 < K; k0 += 32) {
    gload_lds16(gA0 + k0, sAw);
    gload_lds16(gA0 + (size_t)64 * K + k0, sAw + 2048);
    gload_lds16(gB0 + k0, sBw);
    gload_lds16(gB0 + (size_t)64 * K + k0, sBw + 2048);
    __syncthreads();
    h16x8 af[4], bfv[4];
#pragma unroll
    for (int mi = 0; mi < 4; mi++)
      af[mi] = *(const h16x8*)(sA + (wm + mi * 16 + lm) * 32 + ((lh ^ swa) << 3));
#pragma unroll
    for (int ni = 0; ni < 4; ni++)
      bfv[ni] = *(const h16x8*)(sB + (wn + ni * 16 + lm) * 32 + ((lh ^ swa) << 3));
#pragma unroll
    for (int mi = 0; mi < 4; mi++)
#pragma unroll
      for (int ni = 0; ni < 4; ni++)
        acc[mi][ni] = mfma_f16(af[mi], bfv[ni], acc[mi][ni]);
    __syncthreads();
  }
}

// ---------------- GEMM1: qkv = x @ W_attn + b; scatter q,k:[B,Nh,S,Ne], v^T:[B,Nh,Ne,S] ----------------
__global__ __launch_bounds__(256) void k_gemm_qkv(const h16* __restrict__ xb,
                                                  const h16* __restrict__ WTa,
                                                  const float* __restrict__ b_attn,
                                                  h16* __restrict__ qb, h16* __restrict__ kbuf,
                                                  h16* __restrict__ vT) {
  __shared__ __align__(16) h16 sA[128 * 32];
  __shared__ __align__(16) h16 sB[128 * 32];
  f32x4 acc[4][4];
#pragma unroll
  for (int i = 0; i < 4; i++)
#pragma unroll
    for (int j = 0; j < 4; j++) acc[i][j] = (f32x4){0.f, 0.f, 0.f, 0.f};
  const int n0 = blockIdx.x * 128, m0 = blockIdx.y * 128;
  gemm_main(xb, WTa, 1024, m0, n0, sA, sB, acc);

  const int t = threadIdx.x, l = t & 63, w = t >> 6;
  const int lm = l & 15, lh = l >> 4;
  const int wm = (w >> 1) * 64, wn = (w & 1) * 64;
#pragma unroll
  for (int mi = 0; mi < 4; mi++) {
#pragma unroll
    for (int ni = 0; ni < 4; ni++) {
      const int n = n0 + wn + ni * 16 + lm;
      const float bias = b_attn[n];
      const int which = n >> 10, c = n & 1023, h = c >> 6, e = c & 63;
#pragma unroll
      for (int r = 0; r < 4; r++) {
        const int m = m0 + wm + mi * 16 + lh * 4 + r;
        const int b = m >> 11, s = m & 2047;
        const h16 o = (h16)(acc[mi][ni][r] + bias);
        const size_t bh = (size_t)(b * 16 + h);
        if (which == 0)      qb[(bh * 2048 + s) * 64 + e] = o;
        else if (which == 1) kbuf[(bh * 2048 + s) * 64 + e] = o;
        else                 vT[(bh * 64 + e) * 2048 + s] = o;
      }
    }
  }
}

// ---------------- GEMM2: out = y @ W_proj + b (fp32 out) ----------------
__global__ __launch_bounds__(256) void k_gemm_proj(const h16* __restrict__ yb,
                                                   const h16* __restrict__ WTp,
                                                   const float* __restrict__ b_proj,
                                                   float* __restrict__ out) {
  __shared__ __align__(16) h16 sA[128 * 32];
  __shared__ __align__(16) h16 sB[128 * 32];
  f32x4 acc[4][4];
#pragma unroll
  for (int i = 0; i < 4; i++)
#pragma unroll
    for (int j = 0; j < 4; j++) acc[i][j] = (f32x4){0.f, 0.f, 0.f, 0.f};
  const int n0 = blockIdx.x * 128, m0 = blockIdx.y * 128;
  gemm_main(yb, WTp, 1024, m0, n0, sA, sB, acc);

  const int t = threadIdx.x, l = t & 63, w = t >> 6;
  const int lm = l & 15, lh = l >> 4;
  const int wm = (w >> 1) * 64, wn = (w & 1) * 64;
#pragma unroll
  for (int mi = 0; mi < 4; mi++) {
#pragma unroll
    for (int ni = 0; ni < 4; ni++) {
      const int n = n0 + wn + ni * 16 + lm;
      const float bias = b_proj[n];
#pragma unroll
      for (int r = 0; r < 4; r++) {
        const int m = m0 + wm + mi * 16 + lh * 4 + r;
        out[(size_t)m * 1024 + n] = acc[mi][ni][r] + bias;
      }
    }
  }
}

// ---------------- causal flash attention, v4 ----------------
// K/V read DIRECTLY from global (L2-resident: 512KB/head, 8 heads/XCD = 4MB)
// -- no K/V LDS staging, no __syncthreads, waves fully independent (m169).
// Swapped QK^T (mfma(K,Q)): lane(lm,lh) holds S[q=lm][kcol=ct*16+lh*4+r];
// row stats need a 4-lane group reduce (shfl_xor 16,32). P through per-wave
// swizzled LDS; swapped PV (mfma(V^T,P)) keeps q=lane for the output.
__global__ __launch_bounds__(256, 3) void k_attn(const h16* __restrict__ qb,
                                                 const h16* __restrict__ kbuf,
                                                 const h16* __restrict__ vT,
                                                 h16* __restrict__ yb) {
  __shared__ __align__(16) h16 sP[4][2][16 * 64];

  const int bid = blockIdx.x;
  const int bh = bid & 63;          // same-head blocks 64 apart -> same XCD
  const int qt = 15 - (bid >> 6);   // long blocks dispatch first
  const int b = bh >> 4, h = bh & 15;
  const int tid = threadIdx.x, lam = tid & 63, w = tid >> 6;
  const int lm = lam & 15, lh = lam >> 4;
  const int q0 = qt * 128 + w * 32;
  const h16* Q = qb + (size_t)bh * 2048 * 64;
  const h16* Kp = kbuf + (size_t)bh * 2048 * 64;
  const h16* Vp = vT + (size_t)bh * 64 * 2048;

  // Q fragments (B-operand: col=q=lm, k=d), prescaled into exp2 domain
  h16x8 qf[2][2];
#pragma unroll
  for (int rt = 0; rt < 2; rt++)
#pragma unroll
    for (int dc = 0; dc < 2; dc++) {
      h16x8 qv = *(const h16x8*)(Q + (size_t)(q0 + rt * 16 + lm) * 64 + dc * 32 + lh * 8);
      h16x8 o;
#pragma unroll
      for (int i = 0; i < 8; i++) o[i] = (h16)((float)qv[i] * QSCALE);
      qf[rt][dc] = o;
    }

  f32x4 yacc[2][4];
  float m2[2], lw[2];
#pragma unroll
  for (int rt = 0; rt < 2; rt++) {
    m2[rt] = -1e30f;
    lw[rt] = 0.f;
#pragma unroll
    for (int i = 0; i < 4; i++) yacc[rt][i] = (f32x4){0.f, 0.f, 0.f, 0.f};
  }

  for (int kb0 = 0; kb0 <= q0 + 31; kb0 += 64) {
    const bool domask = (kb0 + 63 > q0);
    // K fragments (A-operand: row=kcol=ct*16+lm, k=d) -- direct from L2
    h16x8 kf[4][2];
#pragma unroll
    for (int ct = 0; ct < 4; ct++)
#pragma unroll
      for (int dc = 0; dc < 2; dc++)
        kf[ct][dc] = *(const h16x8*)(Kp + (size_t)(kb0 + ct * 16 + lm) * 64 + dc * 32 + lh * 8);
    // V fragments (A-operand for PV: row=d=dt*16+lm, k=kcol) -- issued early,
    // latency hides under QK^T + softmax
    h16x8 vf[4][2];
#pragma unroll
    for (int dt = 0; dt < 4; dt++)
#pragma unroll
      for (int kc = 0; kc < 2; kc++)
        vf[dt][kc] = *(const h16x8*)(Vp + (size_t)(dt * 16 + lm) * 2048 + kb0 + kc * 32 + lh * 8);

#pragma unroll
    for (int rt = 0; rt < 2; rt++) {
      const int qrow = q0 + rt * 16 + lm;
      f32x4 sv[4];
      __builtin_amdgcn_s_setprio(1);
#pragma unroll
      for (int ct = 0; ct < 4; ct++) {
        f32x4 s = mfma_f16(kf[ct][0], qf[rt][0], (f32x4){0.f, 0.f, 0.f, 0.f});
        sv[ct] = mfma_f16(kf[ct][1], qf[rt][1], s);
      }
      __builtin_amdgcn_s_setprio(0);
      if (domask) {
#pragma unroll
        for (int ct = 0; ct < 4; ct++)
#pragma unroll
          for (int r = 0; r < 4; r++)
            if (kb0 + ct * 16 + lh * 4 + r > qrow) sv[ct][r] = -1e30f;
      }
      // row max: lane-local 16 values, then 4-lane group reduce (lh axis)
      float rm = fmaxf(fmaxf(fmaxf(sv[0][0], sv[0][1]), fmaxf(sv[0][2], sv[0][3])),
                       fmaxf(fmaxf(sv[1][0], sv[1][1]), fmaxf(sv[1][2], sv[1][3])));
      rm = fmaxf(rm, fmaxf(fmaxf(fmaxf(sv[2][0], sv[2][1]), fmaxf(sv[2][2], sv[2][3])),
                           fmaxf(fmaxf(sv[3][0], sv[3][1]), fmaxf(sv[3][2], sv[3][3]))));
      rm = fmaxf(rm, __shfl_xor(rm, 16));
      rm = fmaxf(rm, __shfl_xor(rm, 32));
      // T13 defer-max: rescale only when some row's max grew past THR
      if (!__all(rm <= m2[rt] + THR)) {
        const float nm = fmaxf(m2[rt], rm);
        const float alpha = __builtin_amdgcn_exp2f(m2[rt] - nm);
        m2[rt] = nm;
        lw[rt] *= alpha;
#pragma unroll
        for (int dt = 0; dt < 4; dt++) yacc[rt][dt] *= alpha;
      }
      // p = exp2(s - m); lane-partial sum; packed b32 writes to swizzled P
      const float m = m2[rt];
      float psum = 0.f;
#pragma unroll
      for (int ct = 0; ct < 4; ct++) {
        const float p0 = __builtin_amdgcn_exp2f(sv[ct][0] - m);
        const float p1 = __builtin_amdgcn_exp2f(sv[ct][1] - m);
        const float p2 = __builtin_amdgcn_exp2f(sv[ct][2] - m);
        const float p3 = __builtin_amdgcn_exp2f(sv[ct][3] - m);
        psum += (p0 + p1) + (p2 + p3);
        const fp16x2 u0 = __builtin_amdgcn_cvt_pkrtz(p0, p1);
        const fp16x2 u1 = __builtin_amdgcn_cvt_pkrtz(p2, p3);
        const int base = ct * 16 + lh * 4;
        *(fp16x2*)(&sP[w][rt][lm * 64 + ((base + 0) ^ ((lm & 7) << 3))]) = u0;
        *(fp16x2*)(&sP[w][rt][lm * 64 + ((base + 2) ^ ((lm & 7) << 3))]) = u1;
      }
      lw[rt] += psum;
    }
    // wave-local LDS write->read ordering (per-wave buffers; rule #18)
    asm volatile("s_waitcnt lgkmcnt(0)" ::: "memory");
    __builtin_amdgcn_sched_barrier(0);
    // PV: yacc[rt][dt] += V^T . P  (C: row=d, col=q=lm)
#pragma unroll
    for (int rt = 0; rt < 2; rt++) {
      const h16x8 pf0 = *(const h16x8*)(
          &sP[w][rt][lm * 64 + ((lh * 8) ^ ((lm & 7) << 3))]);
      const h16x8 pf1 = *(const h16x8*)(
          &sP[w][rt][lm * 64 + ((32 + lh * 8) ^ ((lm & 7) << 3))]);
      __builtin_amdgcn_s_setprio(1);
#pragma unroll
      for (int dt = 0; dt < 4; dt++) {
        f32x4 y = mfma_f16(vf[dt][0], pf0, yacc[rt][dt]);
        yacc[rt][dt] = mfma_f16(vf[dt][1], pf1, y);
      }
      __builtin_amdgcn_s_setprio(0);
    }
  }

  // epilogue: group-reduce row sums (lh axis), normalize, 8B packed stores
#pragma unroll
  for (int rt = 0; rt < 2; rt++) {
    float s = lw[rt];
    s += __shfl_xor(s, 16);
    s += __shfl_xor(s, 32);
    const float inv = 1.0f / s;
    const int q = q0 + rt * 16 + lm;
    const size_t yrow = ((size_t)b * 2048 + q) * 1024 + h * 64;
#pragma unroll
    for (int dt = 0; dt < 4; dt++) {
      h16x4 o;
#pragma unroll
      for (int r = 0; r < 4; r++) o[r] = (h16)(yacc[rt][dt][r] * inv);
      *(h16x4*)(yb + yrow + dt * 16 + lh * 4) = o;
    }
  }
}

extern "C" void kernel_launch(void* const* d_in, const int* in_sizes, int n_in,
                              void* d_out, int out_size, void* d_ws, size_t ws_size,
                              hipStream_t stream) {
  const float* x      = (const float*)d_in[0];
  const float* W_attn = (const float*)d_in[1];
  const float* b_attn = (const float*)d_in[2];
  const float* W_proj = (const float*)d_in[3];
  const float* b_proj = (const float*)d_in[4];
  float* out = (float*)d_out;

  char* ws = (char*)d_ws;
  h16* xb   = (h16*)(ws);                 // 16 MB  [8192][1024] fp16 (reused as yb)
  h16* WTa  = (h16*)(ws + 16777216);      // 6 MB   [3072][1024]
  h16* WTp  = (h16*)(ws + 23068672);      // 2 MB   [1024][1024]
  h16* qb   = (h16*)(ws + 25165824);      // 16 MB  [B,Nh,S,Ne]
  h16* kbuf = (h16*)(ws + 41943040);      // 16 MB  [B,Nh,S,Ne]
  h16* vT   = (h16*)(ws + 58720256);      // 16 MB  [B,Nh,Ne,S]
  h16* yb   = xb;                         // reuse x buffer for attention output

  k_cvt<<<dim3(8192 * 1024 / 2048), 256, 0, stream>>>(x, xb, 8192 * 1024);
  k_tr_cvt<<<dim3(3072 / 32, 1024 / 32), 256, 0, stream>>>(W_attn, WTa, 1024, 3072);
  k_tr_cvt<<<dim3(1024 / 32, 1024 / 32), 256, 0, stream>>>(W_proj, WTp, 1024, 1024);
  k_gemm_qkv<<<dim3(3072 / 128, 8192 / 128), 256, 0, stream>>>(xb, WTa, b_attn, qb, kbuf, vT);
  k_attn<<<dim3(64 * 16), 256, 0, stream>>>(qb, kbuf, vT, yb);
  k_gemm_proj<<<dim3(1024 / 128, 8192 / 128), 256, 0, stream>>>(yb, WTp, b_proj, out);
}

// Round 10
// 314.069 us; speedup vs baseline: 1.1820x; 1.1820x over previous
//
#include <hip/hip_runtime.h>
#include <cstdint>
#include <cstddef>

typedef _Float16 h16;
typedef _Float16 h16x4 __attribute__((ext_vector_type(4)));
typedef _Float16 h16x8 __attribute__((ext_vector_type(8)));
typedef __fp16 fp16x2 __attribute__((ext_vector_type(2)));
typedef float f32x4 __attribute__((ext_vector_type(4)));

#define LOG2E 1.44269504088896f
#define QSCALE (0.125f * LOG2E)
#define THR 11.0f

static __device__ __forceinline__ f32x4 mfma_f16(h16x8 a, h16x8 b, f32x4 c) {
  return __builtin_amdgcn_mfma_f32_16x16x32_f16(a, b, c, 0, 0, 0);
}

static __device__ __forceinline__ void gload_lds16(const void* g, void* s) {
  __builtin_amdgcn_global_load_lds(
      (__attribute__((address_space(1))) void*)(uintptr_t)g,
      (__attribute__((address_space(3))) void*)s, 16, 0, 0);
}

// ---------------- fp32 -> fp16 convert (vectorized) ----------------
__global__ __launch_bounds__(256) void k_cvt(const float* __restrict__ in,
                                             h16* __restrict__ out, int n) {
  int i = (blockIdx.x * 256 + threadIdx.x) * 8;
  if (i >= n) return;
  float4 a = *(const float4*)(in + i);
  float4 b = *(const float4*)(in + i + 4);
  h16x8 o;
  o[0] = (h16)a.x; o[1] = (h16)a.y; o[2] = (h16)a.z; o[3] = (h16)a.w;
  o[4] = (h16)b.x; o[5] = (h16)b.y; o[6] = (h16)b.z; o[7] = (h16)b.w;
  *(h16x8*)(out + i) = o;
}

// ---------------- fp32 [R][C] -> fp16 [C][R] transpose-convert ----------------
__global__ __launch_bounds__(256) void k_tr_cvt(const float* __restrict__ in,
                                                h16* __restrict__ out, int R, int C) {
  __shared__ float tile[32][33];
  int c0 = blockIdx.x * 32, r0 = blockIdx.y * 32;
  int tx = threadIdx.x & 31, ty = threadIdx.x >> 5;
#pragma unroll
  for (int i = 0; i < 4; i++) {
    int r = ty + i * 8;
    tile[r][tx] = in[(size_t)(r0 + r) * C + c0 + tx];
  }
  __syncthreads();
#pragma unroll
  for (int i = 0; i < 4; i++) {
    int c = ty + i * 8;
    out[(size_t)(c0 + c) * R + r0 + tx] = (h16)tile[tx][c];
  }
}

// ======== 256x256 tile, BK=32, 8-wave, 4-slot-ring counted-vmcnt GEMM ========
// 512 threads = 8 waves: wr=w>>2 (M-half), wc=w&3 (N-quarter); wave out 128x64.
// LDS ring: 4 slots x (A[256][32] + B[256][32]) = 4 x 32KB = 128KB.
// Stage kt+3 while computing kt (use-distance 6 phases >> HBM latency).
// Per K-tile: 2 phases (miL/miH), 16 MFMA each, raw s_barrier (no vmcnt drain),
// vmcnt(8) once per K-tile (2 staged K-tiles x 4 loads allowed in flight).
// Swizzle: granule g at row holds global granule g ^ ((row>>1)&3)  (validated R8);
// read-side XOR = (lm>>1)&3.
#define SLOT_E 16384   // h16 per slot (A 8192 + B 8192)
#define NTK 32         // K = 1024 / 32

static __device__ __forceinline__ void gemm8p(const h16* __restrict__ A,
                                              const h16* __restrict__ BT,
                                              int m0, int n0, h16* sAB,
                                              f32x4 acc[8][4]) {
  const int tid = threadIdx.x;
  const int lane = tid & 63, w = tid >> 6;
  const int lm = lane & 15, lh = lane >> 4;
  const int wr = w >> 2, wc = w & 3;
  const int rdx = (lm >> 1) & 3;

  // staging geometry (per thread, 2 rounds each for A and B)
  const h16* pA[2];
  const h16* pB[2];
  int dst[2];
#pragma unroll
  for (int r = 0; r < 2; r++) {
    const int idx = tid + r * 512;
    const int srow = idx >> 2;
    const int gsrc = (idx & 3) ^ ((srow >> 1) & 3);
    pA[r] = A + (size_t)(m0 + srow) * 1024 + gsrc * 8;
    pB[r] = BT + (size_t)(n0 + srow) * 1024 + gsrc * 8;
    dst[r] = w * 512 + r * 4096;  // wave-uniform + lane*16B covers idx*16B
  }

  auto stage = [&](int kt) {
    h16* slot = sAB + (kt & 3) * SLOT_E;
    const int k0 = kt * 32;
#pragma unroll
    for (int r = 0; r < 2; r++) {
      gload_lds16(pA[r] + k0, slot + dst[r]);
      gload_lds16(pB[r] + k0, slot + 8192 + dst[r]);
    }
  };

  // prologue: 3 K-tiles in flight; wait kt0 (allow kt1,kt2 = 8 loads)
  stage(0); stage(1); stage(2);
  asm volatile("s_waitcnt vmcnt(8)" ::: "memory");
  __builtin_amdgcn_s_barrier();

  for (int kt = 0; kt < NTK; ++kt) {
    if (kt + 3 < NTK) stage(kt + 3);  // slot (kt+3)&3 freed before kt started
    const h16* sa = sAB + (kt & 3) * SLOT_E;
    const h16* sb = sa + 8192;

    // ---- phase A: miL (mi 0..3) x all ni ----
    h16x8 af[4], bf[4];
#pragma unroll
    for (int mi = 0; mi < 4; mi++)
      af[mi] = *(const h16x8*)(sa + (wr * 128 + mi * 16 + lm) * 32 + ((lh ^ rdx) << 3));
#pragma unroll
    for (int ni = 0; ni < 4; ni++)
      bf[ni] = *(const h16x8*)(sb + (wc * 64 + ni * 16 + lm) * 32 + ((lh ^ rdx) << 3));
    __builtin_amdgcn_sched_barrier(0);
    __builtin_amdgcn_s_barrier();
    asm volatile("s_waitcnt lgkmcnt(0)" ::: "memory");
    __builtin_amdgcn_s_setprio(1);
#pragma unroll
    for (int mi = 0; mi < 4; mi++)
#pragma unroll
      for (int ni = 0; ni < 4; ni++)
        acc[mi][ni] = mfma_f16(af[mi], bf[ni], acc[mi][ni]);
    __builtin_amdgcn_s_setprio(0);
    __builtin_amdgcn_s_barrier();

    // ---- phase B: miH (mi 4..7), reuse bf ----
    h16x8 ag[4];
#pragma unroll
    for (int mi = 0; mi < 4; mi++)
      ag[mi] = *(const h16x8*)(sa + (wr * 128 + (mi + 4) * 16 + lm) * 32 + ((lh ^ rdx) << 3));
    __builtin_amdgcn_sched_barrier(0);
    __builtin_amdgcn_s_barrier();
    asm volatile("s_waitcnt lgkmcnt(0)" ::: "memory");
    __builtin_amdgcn_s_setprio(1);
#pragma unroll
    for (int mi = 0; mi < 4; mi++)
#pragma unroll
      for (int ni = 0; ni < 4; ni++)
        acc[mi + 4][ni] = mfma_f16(ag[mi], bf[ni], acc[mi + 4][ni]);
    __builtin_amdgcn_s_setprio(0);

    // counted wait: kt+1 landed; kt+2/kt+3 stages (8 loads) may stay in flight
    if (kt < NTK - 3)      asm volatile("s_waitcnt vmcnt(8)" ::: "memory");
    else if (kt == NTK - 3) asm volatile("s_waitcnt vmcnt(4)" ::: "memory");
    else if (kt == NTK - 2) asm volatile("s_waitcnt vmcnt(0)" ::: "memory");
    __builtin_amdgcn_s_barrier();
  }
}

// ---------------- GEMM1: qkv = x @ W_attn + b; scatter q,k:[B,Nh,S,Ne], v^T:[B,Nh,Ne,S] ----------------
__global__ __launch_bounds__(512, 1) void k_gemm_qkv(const h16* __restrict__ xb,
                                                     const h16* __restrict__ WTa,
                                                     const float* __restrict__ b_attn,
                                                     h16* __restrict__ qb,
                                                     h16* __restrict__ kbuf,
                                                     h16* __restrict__ vT) {
  __shared__ __align__(16) h16 sAB[4 * SLOT_E];
  const int bid = blockIdx.x;
  const int flat = (bid & 7) * 48 + (bid >> 3);  // bijective XCD swizzle (384%8==0)
  const int mt = flat / 12, nt = flat % 12;
  const int m0 = mt * 256, n0 = nt * 256;
  f32x4 acc[8][4];
#pragma unroll
  for (int i = 0; i < 8; i++)
#pragma unroll
    for (int j = 0; j < 4; j++) acc[i][j] = (f32x4){0.f, 0.f, 0.f, 0.f};
  gemm8p(xb, WTa, m0, n0, sAB, acc);

  const int tid = threadIdx.x, lane = tid & 63, w = tid >> 6;
  const int lm = lane & 15, lh = lane >> 4;
  const int wr = w >> 2, wc = w & 3;
#pragma unroll
  for (int ni = 0; ni < 4; ni++) {
    const int n = n0 + wc * 64 + ni * 16 + lm;
    const float bias = b_attn[n];
    const int which = n >> 10, cc = n & 1023, hh = cc >> 6, e = cc & 63;
#pragma unroll
    for (int mi = 0; mi < 8; mi++) {
#pragma unroll
      for (int r = 0; r < 4; r++) {
        const int m = m0 + wr * 128 + mi * 16 + lh * 4 + r;
        const int b = m >> 11, s = m & 2047;
        const h16 o = (h16)(acc[mi][ni][r] + bias);
        const size_t bh = (size_t)(b * 16 + hh);
        if (which == 0)      qb[(bh * 2048 + s) * 64 + e] = o;
        else if (which == 1) kbuf[(bh * 2048 + s) * 64 + e] = o;
        else                 vT[(bh * 64 + e) * 2048 + s] = o;
      }
    }
  }
}

// ---------------- GEMM2: out = y @ W_proj + b (fp32 out) ----------------
__global__ __launch_bounds__(512, 1) void k_gemm_proj(const h16* __restrict__ yb,
                                                      const h16* __restrict__ WTp,
                                                      const float* __restrict__ b_proj,
                                                      float* __restrict__ out) {
  __shared__ __align__(16) h16 sAB[4 * SLOT_E];
  const int bid = blockIdx.x;
  const int flat = (bid & 7) * 16 + (bid >> 3);  // 128%8==0
  const int mt = flat / 4, nt = flat % 4;
  const int m0 = mt * 256, n0 = nt * 256;
  f32x4 acc[8][4];
#pragma unroll
  for (int i = 0; i < 8; i++)
#pragma unroll
    for (int j = 0; j < 4; j++) acc[i][j] = (f32x4){0.f, 0.f, 0.f, 0.f};
  gemm8p(yb, WTp, m0, n0, sAB, acc);

  const int tid = threadIdx.x, lane = tid & 63, w = tid >> 6;
  const int lm = lane & 15, lh = lane >> 4;
  const int wr = w >> 2, wc = w & 3;
#pragma unroll
  for (int ni = 0; ni < 4; ni++) {
    const int n = n0 + wc * 64 + ni * 16 + lm;
    const float bias = b_proj[n];
#pragma unroll
    for (int mi = 0; mi < 8; mi++) {
#pragma unroll
      for (int r = 0; r < 4; r++) {
        const int m = m0 + wr * 128 + mi * 16 + lh * 4 + r;
        out[(size_t)m * 1024 + n] = acc[mi][ni][r] + bias;
      }
    }
  }
}

// ---------------- causal flash attention (R5 verbatim: staged K/V, 90us) ----------------
__global__ __launch_bounds__(256, 3) void k_attn(const h16* __restrict__ qb,
                                                 const h16* __restrict__ kbuf,
                                                 const h16* __restrict__ vT,
                                                 h16* __restrict__ yb) {
  __shared__ __align__(16) h16 sKt[2][64 * 64];
  __shared__ __align__(16) h16 sVt[2][64 * 64];
  __shared__ __align__(16) h16 sP[4][2][16 * 64];

  const int bid = blockIdx.x;
  const int bh = bid & 63;
  const int qt = 15 - (bid >> 6);
  const int b = bh >> 4, h = bh & 15;
  const int tid = threadIdx.x, lam = tid & 63, w = tid >> 6;
  const int lm = lam & 15, lh = lam >> 4;
  const int q0 = qt * 128 + w * 32;
  const h16* Q = qb + (size_t)bh * 2048 * 64;
  const h16* Kp = kbuf + (size_t)bh * 2048 * 64;
  const h16* Vp = vT + (size_t)bh * 64 * 2048;

  const int srow = lam >> 3;
  const int xo8 = (((lam & 7) ^ (srow & 7)) << 3);

  h16x8 qf[2][2];
#pragma unroll
  for (int rt = 0; rt < 2; rt++)
#pragma unroll
    for (int dc = 0; dc < 2; dc++) {
      h16x8 qv = *(const h16x8*)(Q + (size_t)(q0 + rt * 16 + lm) * 64 + dc * 32 + lh * 8);
      h16x8 o;
#pragma unroll
      for (int i = 0; i < 8; i++) o[i] = (h16)((float)qv[i] * QSCALE);
      qf[rt][dc] = o;
    }

  f32x4 yacc[2][4];
  float m2[2], lw[2];
#pragma unroll
  for (int rt = 0; rt < 2; rt++) {
    m2[rt] = -1e30f;
    lw[rt] = 0.f;
#pragma unroll
    for (int i = 0; i < 4; i++) yacc[rt][i] = (f32x4){0.f, 0.f, 0.f, 0.f};
  }

  const int nsteps = qt * 2 + 2;

#pragma unroll
  for (int i = 0; i < 2; i++) {
    const int seg = 2 * w + i;
    const int r = seg * 8 + srow;
    gload_lds16(Kp + (size_t)r * 64 + xo8, &sKt[0][seg * 512]);
    gload_lds16(Vp + (size_t)r * 2048 + xo8, &sVt[0][seg * 512]);
  }
  asm volatile("s_waitcnt vmcnt(0)" ::: "memory");
  __syncthreads();

  for (int tt = 0; tt < nsteps; ++tt) {
    const int kb0 = tt * 64, cur = tt & 1;
    if (tt + 1 < nsteps) {
      const int kn = kb0 + 64;
#pragma unroll
      for (int i = 0; i < 2; i++) {
        const int seg = 2 * w + i;
        const int r = seg * 8 + srow;
        gload_lds16(Kp + (size_t)(kn + r) * 64 + xo8, &sKt[cur ^ 1][seg * 512]);
        gload_lds16(Vp + (size_t)r * 2048 + kn + xo8, &sVt[cur ^ 1][seg * 512]);
      }
    }
    if (kb0 <= q0 + 31) {
      const bool domask = (kb0 + 63 > q0);
      h16x8 kf[4][2];
#pragma unroll
      for (int ct = 0; ct < 4; ct++)
#pragma unroll
        for (int dc = 0; dc < 2; dc++)
          kf[ct][dc] = *(const h16x8*)(
              &sKt[cur][(ct * 16 + lm) * 64 + ((dc * 32 + lh * 8) ^ ((lm & 7) << 3))]);
      h16x8 vf[4][2];
#pragma unroll
      for (int dt = 0; dt < 4; dt++)
#pragma unroll
        for (int kc = 0; kc < 2; kc++)
          vf[dt][kc] = *(const h16x8*)(
              &sVt[cur][(dt * 16 + lm) * 64 + ((kc * 32 + lh * 8) ^ ((lm & 7) << 3))]);

#pragma unroll
      for (int rt = 0; rt < 2; rt++) {
        const int qrow = q0 + rt * 16 + lm;
        f32x4 sv[4];
        __builtin_amdgcn_s_setprio(1);
#pragma unroll
        for (int ct = 0; ct < 4; ct++) {
          f32x4 s = mfma_f16(kf[ct][0], qf[rt][0], (f32x4){0.f, 0.f, 0.f, 0.f});
          sv[ct] = mfma_f16(kf[ct][1], qf[rt][1], s);
        }
        __builtin_amdgcn_s_setprio(0);
        if (domask) {
#pragma unroll
          for (int ct = 0; ct < 4; ct++)
#pragma unroll
            for (int r = 0; r < 4; r++)
              if (kb0 + ct * 16 + lh * 4 + r > qrow) sv[ct][r] = -1e30f;
        }
        float rm = fmaxf(fmaxf(fmaxf(sv[0][0], sv[0][1]), fmaxf(sv[0][2], sv[0][3])),
                         fmaxf(fmaxf(sv[1][0], sv[1][1]), fmaxf(sv[1][2], sv[1][3])));
        rm = fmaxf(rm, fmaxf(fmaxf(fmaxf(sv[2][0], sv[2][1]), fmaxf(sv[2][2], sv[2][3])),
                             fmaxf(fmaxf(sv[3][0], sv[3][1]), fmaxf(sv[3][2], sv[3][3]))));
        rm = fmaxf(rm, __shfl_xor(rm, 16));
        rm = fmaxf(rm, __shfl_xor(rm, 32));
        if (!__all(rm <= m2[rt] + THR)) {
          const float nm = fmaxf(m2[rt], rm);
          const float alpha = __builtin_amdgcn_exp2f(m2[rt] - nm);
          m2[rt] = nm;
          lw[rt] *= alpha;
#pragma unroll
          for (int dt = 0; dt < 4; dt++) yacc[rt][dt] *= alpha;
        }
        const float m = m2[rt];
        float psum = 0.f;
#pragma unroll
        for (int ct = 0; ct < 4; ct++) {
          const float p0 = __builtin_amdgcn_exp2f(sv[ct][0] - m);
          const float p1 = __builtin_amdgcn_exp2f(sv[ct][1] - m);
          const float p2 = __builtin_amdgcn_exp2f(sv[ct][2] - m);
          const float p3 = __builtin_amdgcn_exp2f(sv[ct][3] - m);
          psum += (p0 + p1) + (p2 + p3);
          const fp16x2 u0 = __builtin_amdgcn_cvt_pkrtz(p0, p1);
          const fp16x2 u1 = __builtin_amdgcn_cvt_pkrtz(p2, p3);
          const int base = ct * 16 + lh * 4;
          *(fp16x2*)(&sP[w][rt][lm * 64 + ((base + 0) ^ ((lm & 7) << 3))]) = u0;
          *(fp16x2*)(&sP[w][rt][lm * 64 + ((base + 2) ^ ((lm & 7) << 3))]) = u1;
        }
        lw[rt] += psum;
      }
#pragma unroll
      for (int rt = 0; rt < 2; rt++) {
        const h16x8 pf0 = *(const h16x8*)(
            &sP[w][rt][lm * 64 + ((lh * 8) ^ ((lm & 7) << 3))]);
        const h16x8 pf1 = *(const h16x8*)(
            &sP[w][rt][lm * 64 + ((32 + lh * 8) ^ ((lm & 7) << 3))]);
        __builtin_amdgcn_s_setprio(1);
#pragma unroll
        for (int dt = 0; dt < 4; dt++) {
          f32x4 y = mfma_f16(vf[dt][0], pf0, yacc[rt][dt]);
          yacc[rt][dt] = mfma_f16(vf[dt][1], pf1, y);
        }
        __builtin_amdgcn_s_setprio(0);
      }
    }
    asm volatile("s_waitcnt vmcnt(0)" ::: "memory");
    __syncthreads();
  }

#pragma unroll
  for (int rt = 0; rt < 2; rt++) {
    float s = lw[rt];
    s += __shfl_xor(s, 16);
    s += __shfl_xor(s, 32);
    const float inv = 1.0f / s;
    const int q = q0 + rt * 16 + lm;
    const size_t yrow = ((size_t)b * 2048 + q) * 1024 + h * 64;
#pragma unroll
    for (int dt = 0; dt < 4; dt++) {
      h16x4 o;
#pragma unroll
      for (int r = 0; r < 4; r++) o[r] = (h16)(yacc[rt][dt][r] * inv);
      *(h16x4*)(yb + yrow + dt * 16 + lh * 4) = o;
    }
  }
}

extern "C" void kernel_launch(void* const* d_in, const int* in_sizes, int n_in,
                              void* d_out, int out_size, void* d_ws, size_t ws_size,
                              hipStream_t stream) {
  const float* x      = (const float*)d_in[0];
  const float* W_attn = (const float*)d_in[1];
  const float* b_attn = (const float*)d_in[2];
  const float* W_proj = (const float*)d_in[3];
  const float* b_proj = (const float*)d_in[4];
  float* out = (float*)d_out;

  char* ws = (char*)d_ws;
  h16* xb   = (h16*)(ws);                 // 16 MB  [8192][1024] fp16 (reused as yb)
  h16* WTa  = (h16*)(ws + 16777216);      // 6 MB   [3072][1024]
  h16* WTp  = (h16*)(ws + 23068672);      // 2 MB   [1024][1024]
  h16* qb   = (h16*)(ws + 25165824);      // 16 MB  [B,Nh,S,Ne]
  h16* kbuf = (h16*)(ws + 41943040);      // 16 MB  [B,Nh,S,Ne]
  h16* vT   = (h16*)(ws + 58720256);      // 16 MB  [B,Nh,Ne,S]
  h16* yb   = xb;                         // reuse x buffer for attention output

  k_cvt<<<dim3(8192 * 1024 / 2048), 256, 0, stream>>>(x, xb, 8192 * 1024);
  k_tr_cvt<<<dim3(3072 / 32, 1024 / 32), 256, 0, stream>>>(W_attn, WTa, 1024, 3072);
  k_tr_cvt<<<dim3(1024 / 32, 1024 / 32), 256, 0, stream>>>(W_proj, WTp, 1024, 1024);
  k_gemm_qkv<<<dim3(384), 512, 0, stream>>>(xb, WTa, b_attn, qb, kbuf, vT);
  k_attn<<<dim3(64 * 16), 256, 0, stream>>>(qb, kbuf, vT, yb);
  k_gemm_proj<<<dim3(128), 512, 0, stream>>>(yb, WTp, b_proj, out);
}